// Round 5
// baseline (169.024 us; speedup 1.0000x reference)
//
#include <hip/hip_runtime.h>

// Problem constants (from reference setup_inputs):
//   image:  (B=4, H=512, W=640, C=16) fp32   (83.9 MB)
//   depth:  (B, H, W) fp32                    (5.2 MB)
//   proj:   (B, 4, 4) fp32
//   out:    (B, H, W, C) fp32                 (83.9 MB)
constexpr int B  = 4;
constexpr int H  = 512;
constexpr int Wd = 640;
constexpr int NPIX_IMG = H * Wd;
constexpr int PXB   = 128;               // output pixels per block (x-contiguous)
constexpr int BLOCK = PXB * 4;           // 512 threads (pixel-major, c4 minor)
constexpr int BPR   = Wd / PXB;          // 5 blocks per image row (exact)
constexpr int GRID  = B * H * BPR;       // 10240 blocks
constexpr int SW    = 144;               // staged window width in pixels
constexpr int XMARG = PXB / 2 + 7;       // x_lo = x0(mid) - 71 -> margin 7/8 px
static_assert(Wd % PXB == 0, "block tiles a row exactly");

// Native vector type for nontemporal builtins (HIP_vector_type is rejected).
typedef float f32x4 __attribute__((ext_vector_type(4)));

// Round-5 theory: 4 scattered gathers/pixel through the global-memory system
// (loaded latency + 2x y-redundancy) are the invariant across all ~51us
// versions. Replace them with LDS reads from a cooperatively-staged,
// sequentially-loaded 2-row window; exact value-checked fallback keeps it
// correct for ANY projection matrix.
__global__ __launch_bounds__(BLOCK, 8) void depth_project_kernel(
    const float* __restrict__ image,
    const float* __restrict__ depth,
    const float* __restrict__ proj,
    float4* __restrict__ out)
{
    __shared__ float4 tile[2][SW][4];    // 18,432 B; [row][col][swizzled c4]
    __shared__ int cons[2];              // consensus {y_hat, x_lo}

    const int blk = blockIdx.x;
    const int b   = blk / (H * BPR);
    const int rem = blk % (H * BPR);
    const int h   = rem / BPR;
    const int wb  = (rem % BPR) * PXB;

    const int tix = threadIdx.x;
    const int c4  = tix & 3;             // float4 group of the 16 channels
    const int pl  = tix >> 2;            // pixel within block (0..127)
    const int w   = wb + pl;
    const int pix = (b * H + h) * Wd + w;

    const float* P = proj + b * 16;      // block-uniform -> scalar loads
    const float x = (float)w;
    const float y = (float)h;
    const float d = __builtin_nontemporal_load(depth + pix);

    float sx = (P[0] * x + P[1] * y + P[2])  * d + P[3];
    float sy = (P[4] * x + P[5] * y + P[6])  * d + P[7];
    float sz = (P[8] * x + P[9] * y + P[10]) * d + P[11];
    float cx = sx / sz;
    float cy = sy / sz;

    float x0f = floorf(cx), y0f = floorf(cy);
    float wx1 = cx - x0f,   wy1 = cy - y0f;
    float wx0 = 1.0f - wx1, wy0 = 1.0f - wy1;
    int x0 = (int)x0f, y0 = (int)y0f;
    int x1 = x0 + 1,   y1 = y0 + 1;

    // consensus window from the middle pixel (clamped to overflow-safe range;
    // any value is CORRECT — misses just take the fallback path)
    if (tix == BLOCK / 2) {
        cons[0] = min(max(y0, -8), H + 8);
        cons[1] = min(max(x0 - XMARG, -2 * SW), Wd + SW);
    }
    __syncthreads();
    const int yhat = cons[0];
    const int xlo  = cons[1];
    const int rid0 = min(max(yhat,     0), H - 1);   // image row held in tile[0]
    const int rid1 = min(max(yhat + 1, 0), H - 1);   // image row held in tile[1]

    // ---- cooperative staging: sequential, coalesced 16B loads ----
    const float4* img4 = (const float4*)image;
    const int ibase = b * (NPIX_IMG * 4);            // float4 units
    for (int e = tix; e < 2 * SW * 4; e += BLOCK) {
        int r   = (e >= SW * 4) ? 1 : 0;
        int rm  = e - r * (SW * 4);
        int col = rm >> 2;
        int c   = rm & 3;
        int xc  = min(max(xlo + col, 0), Wd - 1);    // per-column clamp
        int rid = r ? rid1 : rid0;
        // swizzle c4 slot so 64B-strided pixel columns spread across banks
        tile[r][col][c ^ ((col >> 1) & 3)] = img4[ibase + (rid * Wd + xc) * 4 + c];
    }
    __syncthreads();

    // validity + clamped gather indices (same math as reference)
    float vx0 = (x0 >= 0 && x0 < Wd) ? 1.0f : 0.0f;
    float vx1 = (x1 >= 0 && x1 < Wd) ? 1.0f : 0.0f;
    float vy0 = (y0 >= 0 && y0 < H)  ? 1.0f : 0.0f;
    float vy1 = (y1 >= 0 && y1 < H)  ? 1.0f : 0.0f;

    int x0c = min(max(x0, 0), Wd - 1);
    int x1c = min(max(x1, 0), Wd - 1);
    int y0c = min(max(y0, 0), H - 1);
    int y1c = min(max(y1, 0), H - 1);

    float w00 = wy0 * wx0 * vy0 * vx0;
    float w01 = wy0 * wx1 * vy0 * vx1;
    float w10 = wy1 * wx0 * vy1 * vx0;
    float w11 = wy1 * wx1 * vy1 * vx1;

    // ---- LDS gather with exact value-checked fallback ----
    const int j0 = x0c - xlo, j1 = x1c - xlo;
    const bool jok0 = (unsigned)j0 < (unsigned)SW;
    const bool jok1 = (unsigned)j1 < (unsigned)SW;
    const int rs0 = (y0c == rid0) ? 0 : ((y0c == rid1) ? 1 : -1);
    const int rs1 = (y1c == rid0) ? 0 : ((y1c == rid1) ? 1 : -1);
    const bool h00 = jok0 && (rs0 >= 0);
    const bool h01 = jok1 && (rs0 >= 0);
    const bool h10 = jok0 && (rs1 >= 0);
    const bool h11 = jok1 && (rs1 >= 0);

    const int j0s = min(max(j0, 0), SW - 1);
    const int j1s = min(max(j1, 0), SW - 1);
    const int r0s = max(rs0, 0);
    const int r1s = max(rs1, 0);
    const int sl0 = c4 ^ ((j0s >> 1) & 3);
    const int sl1 = c4 ^ ((j1s >> 1) & 3);

    float4 g00 = tile[r0s][j0s][sl0];
    float4 g01 = tile[r0s][j1s][sl1];
    float4 g10 = tile[r1s][j0s][sl0];
    float4 g11 = tile[r1s][j1s][sl1];

    if (!(h00 && h01 && h10 && h11)) {   // rare: row-crossing / clamp / wild matrix
        const float4* ib = img4 + ibase;
        if (!h00) g00 = ib[(y0c * Wd + x0c) * 4 + c4];
        if (!h01) g01 = ib[(y0c * Wd + x1c) * 4 + c4];
        if (!h10) g10 = ib[(y1c * Wd + x0c) * 4 + c4];
        if (!h11) g11 = ib[(y1c * Wd + x1c) * 4 + c4];
    }

    f32x4 r;
    r.x = g00.x * w00 + g01.x * w01 + g10.x * w10 + g11.x * w11;
    r.y = g00.y * w00 + g01.y * w01 + g10.y * w10 + g11.y * w11;
    r.z = g00.z * w00 + g01.z * w01 + g10.z * w10 + g11.z * w11;
    r.w = g00.w * w00 + g01.w * w01 + g10.w * w10 + g11.w * w11;

    // write-once stream: nontemporal so stores don't evict the image from L3
    f32x4* out_v = (f32x4*)out;
    __builtin_nontemporal_store(r, out_v + pix * 4 + c4);
}

extern "C" void kernel_launch(void* const* d_in, const int* in_sizes, int n_in,
                              void* d_out, int out_size, void* d_ws, size_t ws_size,
                              hipStream_t stream) {
    const float* image = (const float*)d_in[0];
    const float* depth = (const float*)d_in[1];
    const float* proj  = (const float*)d_in[2];
    float4* out = (float4*)d_out;

    depth_project_kernel<<<GRID, BLOCK, 0, stream>>>(image, depth, proj, out);
}

// Round 7
// 158.422 us; speedup vs baseline: 1.0669x; 1.0669x over previous
//
#include <hip/hip_runtime.h>

// Problem constants (from reference setup_inputs):
//   image:  (B=4, H=512, W=640, C=16) fp32   (83.9 MB)
//   depth:  (B, H, W) fp32                    (5.2 MB)
//   proj:   (B, 4, 4) fp32
//   out:    (B, H, W, C) fp32                 (83.9 MB)
constexpr int B  = 4;
constexpr int H  = 512;
constexpr int Wd = 640;
constexpr int NPIX_IMG = H * Wd;
constexpr int BLOCK = 256;
constexpr int PIXB  = BLOCK / 4;           // 64 pixels per block
constexpr int BPR   = Wd / PIXB;           // 10 blocks per row (exact)
constexpr int BLOCKS_PER_IMG = H * BPR;    // 5120
constexpr int GRID  = 2 * BLOCKS_PER_IMG;  // 10240 (b=0,1; each thread also does b+2)
static_assert(Wd % PIXB == 0, "block tiles a row exactly");
static_assert(GRID * BLOCK == 2 * NPIX_IMG * 4, "prefetch covers half the image per stream");

// Native vector type for nontemporal builtins (HIP_vector_type is rejected).
typedef float f32x4 __attribute__((ext_vector_type(4)));

// Round-6 theory: every version pins at ~2.9 TB/s combined HBM traffic =
// Little's-law starvation (~45 outstanding lines/CU at ~1000cy latency),
// because each wave has ONE dependent chain in flight. Round 3's MLP test
// was void (VGPR=32 proves the compiler serialized it). Fix: 2 fully
// independent pixel chains per thread (images b and b+2) as pure scalar
// code + __launch_bounds__(256,4) for a 128-VGPR budget, plus round-4's
// sequential prefetch so gathers hit L2/L3 (shorter chains).
__global__ __launch_bounds__(256, 4) void depth_project_kernel(
    const float* __restrict__ image,
    const float* __restrict__ depth,
    const float* __restrict__ proj,
    float4* __restrict__ out)
{
    const int blk = blockIdx.x;
    const int tix = threadIdx.x;

    // ---- sequential cache-allocating prefetch of both image halves ----
    const f32x4* img_v = (const f32x4*)image;
    const int pfi = blk * BLOCK + tix;
    f32x4 pf0 = img_v[pfi];
    f32x4 pf1 = img_v[2 * NPIX_IMG * 4 + pfi];

    // b, h block-uniform: SALU math, proj reads become s_loads.
    const int b0  = blk / BLOCKS_PER_IMG;          // 0 or 1
    const int rem = blk % BLOCKS_PER_IMG;
    const int h   = rem / BPR;
    const int wb  = (rem % BPR) * PIXB;
    const int b1  = b0 + 2;

    const int c4 = tix & 3;
    const int pl = tix >> 2;
    const int w  = wb + pl;
    const int pixA = (b0 * H + h) * Wd + w;
    const int pixB = (b1 * H + h) * Wd + w;

    // two independent depth loads in flight
    const float dA = __builtin_nontemporal_load(depth + pixA);
    const float dB = __builtin_nontemporal_load(depth + pixB);

    const float* PA = proj + b0 * 16;
    const float* PB = proj + b1 * 16;
    const float x = (float)w;
    const float y = (float)h;

    // ---- chain A coords ----
    float sxA = (PA[0] * x + PA[1] * y + PA[2])  * dA + PA[3];
    float syA = (PA[4] * x + PA[5] * y + PA[6])  * dA + PA[7];
    float szA = (PA[8] * x + PA[9] * y + PA[10]) * dA + PA[11];
    float cxA = sxA / szA, cyA = syA / szA;
    // ---- chain B coords (independent; divides overlap) ----
    float sxB = (PB[0] * x + PB[1] * y + PB[2])  * dB + PB[3];
    float syB = (PB[4] * x + PB[5] * y + PB[6])  * dB + PB[7];
    float szB = (PB[8] * x + PB[9] * y + PB[10]) * dB + PB[11];
    float cxB = sxB / szB, cyB = syB / szB;

    float x0fA = floorf(cxA), y0fA = floorf(cyA);
    float wx1A = cxA - x0fA,  wy1A = cyA - y0fA;
    float wx0A = 1.0f - wx1A, wy0A = 1.0f - wy1A;
    int x0A = (int)x0fA, y0A = (int)y0fA, x1A = x0A + 1, y1A = y0A + 1;

    float x0fB = floorf(cxB), y0fB = floorf(cyB);
    float wx1B = cxB - x0fB,  wy1B = cyB - y0fB;
    float wx0B = 1.0f - wx1B, wy0B = 1.0f - wy1B;
    int x0B = (int)x0fB, y0B = (int)y0fB, x1B = x0B + 1, y1B = y0B + 1;

    float vx0A = (x0A >= 0 && x0A < Wd) ? 1.0f : 0.0f;
    float vx1A = (x1A >= 0 && x1A < Wd) ? 1.0f : 0.0f;
    float vy0A = (y0A >= 0 && y0A < H)  ? 1.0f : 0.0f;
    float vy1A = (y1A >= 0 && y1A < H)  ? 1.0f : 0.0f;
    float vx0B = (x0B >= 0 && x0B < Wd) ? 1.0f : 0.0f;
    float vx1B = (x1B >= 0 && x1B < Wd) ? 1.0f : 0.0f;
    float vy0B = (y0B >= 0 && y0B < H)  ? 1.0f : 0.0f;
    float vy1B = (y1B >= 0 && y1B < H)  ? 1.0f : 0.0f;

    int x0cA = min(max(x0A, 0), Wd - 1), x1cA = min(max(x1A, 0), Wd - 1);
    int y0cA = min(max(y0A, 0), H - 1),  y1cA = min(max(y1A, 0), H - 1);
    int x0cB = min(max(x0B, 0), Wd - 1), x1cB = min(max(x1B, 0), Wd - 1);
    int y0cB = min(max(y0B, 0), H - 1),  y1cB = min(max(y1B, 0), H - 1);

    float w00A = wy0A * wx0A * vy0A * vx0A, w01A = wy0A * wx1A * vy0A * vx1A;
    float w10A = wy1A * wx0A * vy1A * vx0A, w11A = wy1A * wx1A * vy1A * vx1A;
    float w00B = wy0B * wx0B * vy0B * vx0B, w01B = wy0B * wx1B * vy0B * vx1B;
    float w10B = wy1B * wx0B * vy1B * vx0B, w11B = wy1B * wx1B * vy1B * vx1B;

    // keep prefetch loads alive (no DCE)
    asm volatile("" :: "v"(pf0.x), "v"(pf0.y), "v"(pf0.z), "v"(pf0.w),
                       "v"(pf1.x), "v"(pf1.y), "v"(pf1.z), "v"(pf1.w));

    // ---- 8 independent gathers in flight ----
    const float4* img4 = (const float4*)image;
    const int baseA = b0 * (NPIX_IMG * 4);
    const int baseB = b1 * (NPIX_IMG * 4);
    float4 a00 = img4[baseA + (y0cA * Wd + x0cA) * 4 + c4];
    float4 a01 = img4[baseA + (y0cA * Wd + x1cA) * 4 + c4];
    float4 a10 = img4[baseA + (y1cA * Wd + x0cA) * 4 + c4];
    float4 a11 = img4[baseA + (y1cA * Wd + x1cA) * 4 + c4];
    float4 g00 = img4[baseB + (y0cB * Wd + x0cB) * 4 + c4];
    float4 g01 = img4[baseB + (y0cB * Wd + x1cB) * 4 + c4];
    float4 g10 = img4[baseB + (y1cB * Wd + x0cB) * 4 + c4];
    float4 g11 = img4[baseB + (y1cB * Wd + x1cB) * 4 + c4];

    f32x4 rA, rB;
    rA.x = a00.x * w00A + a01.x * w01A + a10.x * w10A + a11.x * w11A;
    rA.y = a00.y * w00A + a01.y * w01A + a10.y * w10A + a11.y * w11A;
    rA.z = a00.z * w00A + a01.z * w01A + a10.z * w10A + a11.z * w11A;
    rA.w = a00.w * w00A + a01.w * w01A + a10.w * w10A + a11.w * w11A;
    rB.x = g00.x * w00B + g01.x * w01B + g10.x * w10B + g11.x * w11B;
    rB.y = g00.y * w00B + g01.y * w01B + g10.y * w10B + g11.y * w11B;
    rB.z = g00.z * w00B + g01.z * w01B + g10.z * w10B + g11.z * w11B;
    rB.w = g00.w * w00B + g01.w * w01B + g10.w * w10B + g11.w * w11B;

    // write-once streams: nontemporal so stores don't evict the image
    f32x4* out_v = (f32x4*)out;
    __builtin_nontemporal_store(rA, out_v + pixA * 4 + c4);
    __builtin_nontemporal_store(rB, out_v + pixB * 4 + c4);
}

extern "C" void kernel_launch(void* const* d_in, const int* in_sizes, int n_in,
                              void* d_out, int out_size, void* d_ws, size_t ws_size,
                              hipStream_t stream) {
    const float* image = (const float*)d_in[0];
    const float* depth = (const float*)d_in[1];
    const float* proj  = (const float*)d_in[2];
    float4* out = (float4*)d_out;

    depth_project_kernel<<<GRID, BLOCK, 0, stream>>>(image, depth, proj, out);
}

// Round 8
// 154.370 us; speedup vs baseline: 1.0949x; 1.0263x over previous
//
#include <hip/hip_runtime.h>

// Problem constants (from reference setup_inputs):
//   image:  (B=4, H=512, W=640, C=16) fp32   (83.9 MB)
//   depth:  (B, H, W) fp32                    (5.2 MB)
//   proj:   (B, 4, 4) fp32
//   out:    (B, H, W, C) fp32                 (83.9 MB)
constexpr int B  = 4;
constexpr int H  = 512;
constexpr int Wd = 640;
constexpr int NPIX_IMG = H * Wd;
constexpr int BLOCK = 256;
constexpr int PIXB  = BLOCK / 4;            // 64 pixels per block
constexpr int BPR   = Wd / PIXB;            // 10 blocks per row (exact)
constexpr int BLOCKS_PER_IMG = H * BPR;     // 5120
constexpr int GRID  = B * BLOCKS_PER_IMG;   // 20480 blocks
constexpr int KPF   = 1024;                 // prefetch lead, in blocks (~2.5us)
static_assert(Wd % PIXB == 0, "block tiles a row exactly");
static_assert(GRID * BLOCK * 16 == B * NPIX_IMG * 64, "prefetch covers image exactly");

// Native vector type for nontemporal builtins (HIP_vector_type is rejected).
typedef float f32x4 __attribute__((ext_vector_type(4)));

// Round-8 theory: achieved read BW pins at ~1.2-1.4 TB/s in every version =
// per-CU outstanding-miss slots x HBM-miss latency (Little's law at the TCP
// level). r4/r7's prefetch stalled the wave on its own prefetch (asm consume
// placed before the gathers), so it couldn't help. Fix: NON-BLOCKING
// prefetch-ahead — block i streams block (i+K)'s image+depth chunks and only
// consumes them after the store. Critical-path loads (depth + gathers) then
// hit L2/L3 (~250cy) because block i-K warmed them ~2.5us earlier; the
// HBM-miss stream is sequential (row-buffer friendly) and never stalls a wave.
__global__ __launch_bounds__(256) void depth_project_kernel(
    const float* __restrict__ image,
    const float* __restrict__ depth,
    const float* __restrict__ proj,
    float4* __restrict__ out)
{
    const int blk = blockIdx.x;
    const int tix = threadIdx.x;

    // b, h block-uniform: SALU math, proj reads become s_loads.
    const int b   = blk / BLOCKS_PER_IMG;
    const int rem = blk % BLOCKS_PER_IMG;
    const int h   = rem / BPR;
    const int wb  = (rem % BPR) * PIXB;

    const int c4 = tix & 3;
    const int pl = tix >> 2;
    const int w  = wb + pl;
    const int pix = (b * H + h) * Wd + w;

    // critical-path depth load — issued first (in-order vmcnt retirement:
    // younger prefetch loads then never gate the depth wait)
    const float d = depth[pix];

    // ---- fire-and-forget prefetch of block (blk+KPF)'s working set ----
    // image chunk: 256 threads x 16B = 4KB = exactly that block's 64 pixels.
    // depth chunk: its 64 depth values (wave 0 only).
    const f32x4* img_v = (const f32x4*)image;
    f32x4 pf = {0.0f, 0.0f, 0.0f, 0.0f};
    float pfd = 0.0f;
    const int pblk = blk + KPF;
    if (pblk < GRID) {
        pf = img_v[pblk * BLOCK + tix];
        if (tix < PIXB) pfd = depth[pblk * PIXB + tix];
    }

    const float* P = proj + b * 16;   // uniform -> scalar loads
    const float x = (float)w;
    const float y = (float)h;

    float sx = (P[0] * x + P[1] * y + P[2])  * d + P[3];
    float sy = (P[4] * x + P[5] * y + P[6])  * d + P[7];
    float sz = (P[8] * x + P[9] * y + P[10]) * d + P[11];
    float cx = sx / sz;
    float cy = sy / sz;

    float x0f = floorf(cx), y0f = floorf(cy);
    float wx1 = cx - x0f,   wy1 = cy - y0f;
    float wx0 = 1.0f - wx1, wy0 = 1.0f - wy1;
    int x0 = (int)x0f, y0 = (int)y0f;
    int x1 = x0 + 1,   y1 = y0 + 1;

    float vx0 = (x0 >= 0 && x0 < Wd) ? 1.0f : 0.0f;
    float vx1 = (x1 >= 0 && x1 < Wd) ? 1.0f : 0.0f;
    float vy0 = (y0 >= 0 && y0 < H)  ? 1.0f : 0.0f;
    float vy1 = (y1 >= 0 && y1 < H)  ? 1.0f : 0.0f;

    int x0c = min(max(x0, 0), Wd - 1);
    int x1c = min(max(x1, 0), Wd - 1);
    int y0c = min(max(y0, 0), H - 1);
    int y1c = min(max(y1, 0), H - 1);

    float w00 = wy0 * wx0 * vy0 * vx0;
    float w01 = wy0 * wx1 * vy0 * vx1;
    float w10 = wy1 * wx0 * vy1 * vx0;
    float w11 = wy1 * wx1 * vy1 * vx1;

    // gathers: should hit L2/L3 thanks to block (blk-KPF)'s prefetch
    const float4* img4 = (const float4*)image;
    const int base_b = b * (NPIX_IMG * 4);   // float4 units
    float4 g00 = img4[base_b + (y0c * Wd + x0c) * 4 + c4];
    float4 g01 = img4[base_b + (y0c * Wd + x1c) * 4 + c4];
    float4 g10 = img4[base_b + (y1c * Wd + x0c) * 4 + c4];
    float4 g11 = img4[base_b + (y1c * Wd + x1c) * 4 + c4];

    f32x4 r;
    r.x = g00.x * w00 + g01.x * w01 + g10.x * w10 + g11.x * w11;
    r.y = g00.y * w00 + g01.y * w01 + g10.y * w10 + g11.y * w11;
    r.z = g00.z * w00 + g01.z * w01 + g10.z * w10 + g11.z * w11;
    r.w = g00.w * w00 + g01.w * w01 + g10.w * w10 + g11.w * w11;

    // write-once stream: nontemporal so stores don't evict the image from L3
    f32x4* out_v = (f32x4*)out;
    __builtin_nontemporal_store(r, out_v + pix * 4 + c4);

    // consume the prefetch LAST — the wave never stalls on it mid-flight
    asm volatile("" :: "v"(pf.x), "v"(pf.y), "v"(pf.z), "v"(pf.w), "v"(pfd));
}

extern "C" void kernel_launch(void* const* d_in, const int* in_sizes, int n_in,
                              void* d_out, int out_size, void* d_ws, size_t ws_size,
                              hipStream_t stream) {
    const float* image = (const float*)d_in[0];
    const float* depth = (const float*)d_in[1];
    const float* proj  = (const float*)d_in[2];
    float4* out = (float4*)d_out;

    depth_project_kernel<<<GRID, BLOCK, 0, stream>>>(image, depth, proj, out);
}